// Round 14
// baseline (1582.118 us; speedup 1.0000x reference)
//
#include <hip/hip_runtime.h>

#define D 128
#define SCAN_CH 1024
#define SA_STRIDE 136   // fp16 units; 272B row
#define SC_STRIDE 132   // fp32 units; 528B row
#define NPB 64          // nodes per conv block
#define CONV_THREADS 512

typedef _Float16 f16x8 __attribute__((ext_vector_type(8)));
typedef float f32x4 __attribute__((ext_vector_type(4)));

// ---------------- CSR build (XCD-affinity: blockIdx%8 owns dst-range) ----------------

__global__ void hist_kernel(const int* __restrict__ dst, int* __restrict__ counts,
                            int E, int N) {
  int range = blockIdx.x & 7;
  int lo = (int)(((long long)N * range) >> 3);
  int hi = (int)(((long long)N * (range + 1)) >> 3);
  int stride = (gridDim.x >> 3) * blockDim.x;
  for (int e = (blockIdx.x >> 3) * blockDim.x + threadIdx.x; e < E; e += stride) {
    int d = dst[e];
    if (d >= lo && d < hi) atomicAdd(&counts[d], 1);
  }
}

__global__ void fill_kernel(const int* __restrict__ src, const int* __restrict__ dst,
    int* __restrict__ fillp, int* __restrict__ csr_src, int E, int N) {
  int range = blockIdx.x & 7;
  int lo = (int)(((long long)N * range) >> 3);
  int hi = (int)(((long long)N * (range + 1)) >> 3);
  int stride = (gridDim.x >> 3) * blockDim.x;
  for (int e = (blockIdx.x >> 3) * blockDim.x + threadIdx.x; e < E; e += stride) {
    int d = dst[e];
    if (d >= lo && d < hi) {
      int s = src[e];
      int p = atomicAdd(&fillp[d], 1);
      csr_src[p] = s;
    }
  }
}

// dnr[n] = (dn = 1/sqrt(deg+1), rdn = sqrt(deg+1))
__global__ void dis_kernel(const int* __restrict__ counts, float2* __restrict__ dnr, int N) {
  int n = blockIdx.x * blockDim.x + threadIdx.x;
  if (n < N) {
    float c = (float)counts[n] + 1.0f;
    dnr[n] = make_float2(rsqrtf(c), sqrtf(c));
  }
}

__global__ __launch_bounds__(256) void scan_phaseA(const int* __restrict__ counts,
    int* __restrict__ blksum, int N) {
  __shared__ int red[256];
  int base = blockIdx.x * SCAN_CH;
  int t = threadIdx.x;
  int s = 0;
  #pragma unroll
  for (int j = 0; j < 4; ++j) {
    int idx = base + t * 4 + j;
    if (idx < N) s += counts[idx];
  }
  red[t] = s;
  __syncthreads();
  for (int d = 128; d > 0; d >>= 1) {
    if (t < d) red[t] += red[t + d];
    __syncthreads();
  }
  if (t == 0) blksum[blockIdx.x] = red[0];
}

__global__ __launch_bounds__(1024) void scan_phaseB(int* __restrict__ blksum, int NB) {
  __shared__ int sa[1024], sb[1024];
  int t = threadIdx.x;
  int v = (t < NB) ? blksum[t] : 0;
  sa[t] = v;
  __syncthreads();
  int* a = sa; int* b = sb;
  for (int d = 1; d < 1024; d <<= 1) {
    int val = a[t] + ((t >= d) ? a[t - d] : 0);
    b[t] = val;
    __syncthreads();
    int* tmp = a; a = b; b = tmp;
  }
  if (t < NB) blksum[t] = a[t] - v;  // exclusive
}

__global__ __launch_bounds__(256) void scan_phaseC(const int* __restrict__ counts,
    const int* __restrict__ blksum, int* __restrict__ row_ptr, int* __restrict__ fillp, int N) {
  __shared__ int ra[256], rb[256];
  int base = blockIdx.x * SCAN_CH;
  int t = threadIdx.x;
  int v[4]; int s = 0;
  #pragma unroll
  for (int j = 0; j < 4; ++j) {
    int idx = base + t * 4 + j;
    v[j] = (idx < N) ? counts[idx] : 0;
    s += v[j];
  }
  ra[t] = s;
  __syncthreads();
  int* a = ra; int* b = rb;
  for (int d = 1; d < 256; d <<= 1) {
    int val = a[t] + ((t >= d) ? a[t - d] : 0);
    b[t] = val;
    __syncthreads();
    int* tmp = a; a = b; b = tmp;
  }
  int excl = a[t] - s + blksum[blockIdx.x];
  #pragma unroll
  for (int j = 0; j < 4; ++j) {
    int idx = base + t * 4 + j;
    if (idx < N) {
      row_ptr[idx] = excl;
      fillp[idx] = excl;
      excl += v[j];
      if (idx == N - 1) row_ptr[N] = excl;
    }
  }
}

// ---------------- one-time conversions ----------------

// hs0 = dn * x[n] (fp16 gather table); x16 = fp16(x) (residual stream seed)
__global__ void conv_x_kernel(const float* __restrict__ x, const float2* __restrict__ dnr,
    _Float16* __restrict__ hs, _Float16* __restrict__ x16, int total8) {
  int i = blockIdx.x * blockDim.x + threadIdx.x;
  if (i >= total8) return;
  int node = i >> 4;
  float dn = dnr[node].x;
  const float4* p = (const float4*)(x + (size_t)i * 8);
  float4 a = p[0], b = p[1];
  f16x8 v, w;
  v[0] = (_Float16)(dn * a.x); v[1] = (_Float16)(dn * a.y);
  v[2] = (_Float16)(dn * a.z); v[3] = (_Float16)(dn * a.w);
  v[4] = (_Float16)(dn * b.x); v[5] = (_Float16)(dn * b.y);
  v[6] = (_Float16)(dn * b.z); v[7] = (_Float16)(dn * b.w);
  w[0] = (_Float16)a.x; w[1] = (_Float16)a.y; w[2] = (_Float16)a.z; w[3] = (_Float16)a.w;
  w[4] = (_Float16)b.x; w[5] = (_Float16)b.y; w[6] = (_Float16)b.z; w[7] = (_Float16)b.w;
  *(f16x8*)(hs + (size_t)i * 8) = v;
  *(f16x8*)(x16 + (size_t)i * 8) = w;
}

// Wf layout: [L][kb(4)][nb(8)][lane(64)] of f16x8 (B fragment, K-slice 8)
__global__ void repack_w_kernel(const float* __restrict__ Ws, _Float16* __restrict__ Wf, int total) {
  int t = blockIdx.x * blockDim.x + threadIdx.x;
  if (t >= total) return;
  int lane = t & 63;
  int nb = (t >> 6) & 7;
  int kb = (t >> 9) & 3;
  int l = t >> 11;
  int col = nb * 16 + (lane & 15);
  int k0 = kb * 32 + (lane >> 4) * 8;
  const float* w = Ws + (size_t)l * D * D;
  f16x8 v;
  #pragma unroll
  for (int j = 0; j < 8; ++j) v[j] = (_Float16)w[(k0 + j) * D + col];
  *(f16x8*)(Wf + (size_t)t * 8) = v;
}

// ---------------- Fused conv ----------------
// conv_n = [dn*(sum_e hs[src_e] + hs[n])] @ W + b   (self-loop in gather)
// Gather: whole wave per node (4 edge-quadrants x unroll 2 = 8 rows in flight,
// wave-uniform loop bounds -> no intra-wave divergence), shfl_xor combine.
// flags: 1=+init16in, 2=write init16out, 4=relu, 8=+h (own*rdn), 16=write hs_out,
//        32=write out (fp32 final)
__global__ __launch_bounds__(CONV_THREADS) void conv_fused_kernel(
    const _Float16* __restrict__ hs, const int* __restrict__ row_ptr,
    const int* __restrict__ csr_src, const float2* __restrict__ dnr,
    const f16x8* __restrict__ Wf, const float* __restrict__ bias,
    const _Float16* __restrict__ init16in, _Float16* __restrict__ init16out,
    float* __restrict__ out, _Float16* __restrict__ hs_out, int N, int flags) {
  __shared__ __align__(16) char smem[NPB * SC_STRIDE * 4];  // sA and sC alias
  _Float16* sA = (_Float16*)smem;
  float* sC = (float*)smem;
  int tid = threadIdx.x;
  int node0 = blockIdx.x * NPB;
  int wave = tid >> 6, lane = tid & 63;
  int es = lane >> 4;         // edge quadrant 0..3
  int li = lane & 15;
  int c0 = li * 8;

  // ---- B fragments first: in flight under the gather ----
  f16x8 bf[4];
  #pragma unroll
  for (int kb = 0; kb < 4; ++kb)
    bf[kb] = Wf[(kb * 8 + wave) * 64 + lane];

  // ---- gather: whole wave per node; 8 nodes per wave ----
  #pragma unroll 2
  for (int k = 0; k < 8; ++k) {
    int lr = wave * 8 + k;
    int n = node0 + lr;
    if (n >= N) break;        // wave-uniform
    float acc[8];
    #pragma unroll
    for (int j = 0; j < 8; ++j) acc[j] = 0.f;
    int beg = row_ptr[n], end = row_ptr[n + 1];
    int e = beg + es;
    for (; e + 4 < end; e += 8) {
      int s0 = csr_src[e];
      int s1 = csr_src[e + 4];
      f16x8 v0 = *(const f16x8*)&hs[(size_t)s0 * D + c0];
      f16x8 v1 = *(const f16x8*)&hs[(size_t)s1 * D + c0];
      #pragma unroll
      for (int j = 0; j < 8; ++j) acc[j] += (float)v0[j] + (float)v1[j];
    }
    for (; e < end; e += 4) {
      int s = csr_src[e];
      f16x8 v = *(const f16x8*)&hs[(size_t)s * D + c0];
      #pragma unroll
      for (int j = 0; j < 8; ++j) acc[j] += (float)v[j];
    }
    // combine quadrants: lanes differing in bits 4,5 hold partial sums of same slice
    #pragma unroll
    for (int j = 0; j < 8; ++j) {
      acc[j] += __shfl_xor(acc[j], 16, 64);
      acc[j] += __shfl_xor(acc[j], 32, 64);
    }
    if (es == 0) {
      f16x8 own = *(const f16x8*)&hs[(size_t)n * D + c0];
      float dn = dnr[n].x;
      f16x8 g;
      #pragma unroll
      for (int j = 0; j < 8; ++j) g[j] = (_Float16)(dn * (acc[j] + (float)own[j]));
      *(f16x8*)&sA[lr * SA_STRIDE + c0] = g;
    }
  }
  __syncthreads();

  // ---- MFMA: 64x128 A (4 row-tiles) x per-wave 16 cols ----
  f32x4 ca[4];
  #pragma unroll
  for (int rt = 0; rt < 4; ++rt) ca[rt] = (f32x4){0, 0, 0, 0};
  #pragma unroll
  for (int rt = 0; rt < 4; ++rt) {
    #pragma unroll
    for (int kb = 0; kb < 4; ++kb) {
      f16x8 a = *(const f16x8*)&sA[(rt * 16 + (lane & 15)) * SA_STRIDE + kb * 32 + (lane >> 4) * 8];
      ca[rt] = __builtin_amdgcn_mfma_f32_16x16x32_f16(a, bf[kb], ca[rt], 0, 0, 0);
    }
  }
  __syncthreads();   // all sA reads done before sC overwrites the same LDS

  // ---- stage C ----
  {
    int colb = wave * 16 + (lane & 15);
    int rowb = (lane >> 4) * 4;
    #pragma unroll
    for (int rt = 0; rt < 4; ++rt)
      #pragma unroll
      for (int r = 0; r < 4; ++r)
        sC[(rt * 16 + rowb + r) * SC_STRIDE + colb] = ca[rt][r];
  }
  __syncthreads();

  // ---- epilogue: 2 passes of 32 nodes; thread handles 8 features ----
  int ng = tid >> 4;
  float4 b0 = *(const float4*)&bias[c0];
  float4 b1 = *(const float4*)&bias[c0 + 4];
  #pragma unroll
  for (int k = 0; k < 2; ++k) {
    int lr = ng + 32 * k;
    int n = node0 + lr;
    if (n >= N) continue;
    float v[8];
    float4 s0 = *(const float4*)&sC[lr * SC_STRIDE + c0];
    float4 s1 = *(const float4*)&sC[lr * SC_STRIDE + c0 + 4];
    v[0] = s0.x + b0.x; v[1] = s0.y + b0.y; v[2] = s0.z + b0.z; v[3] = s0.w + b0.w;
    v[4] = s1.x + b1.x; v[5] = s1.y + b1.y; v[6] = s1.z + b1.z; v[7] = s1.w + b1.w;
    size_t off = (size_t)n * D + c0;
    float2 d2 = dnr[n];
    if (flags & 8) {     // h-add: h = hs_own * rdn (L1/L2-hot re-read)
      f16x8 own = *(const f16x8*)&hs[off];
      float rd = d2.y;
      #pragma unroll
      for (int j = 0; j < 8; ++j) v[j] += (float)own[j] * rd;
    }
    if (flags & 1) {
      f16x8 iv = *(const f16x8*)&init16in[off];
      #pragma unroll
      for (int j = 0; j < 8; ++j) v[j] += (float)iv[j];
    }
    if (flags & 2) {
      f16x8 o;
      #pragma unroll
      for (int j = 0; j < 8; ++j) o[j] = (_Float16)v[j];
      *(f16x8*)&init16out[off] = o;
    }
    if (flags & 4) {
      #pragma unroll
      for (int j = 0; j < 8; ++j) v[j] = fmaxf(v[j], 0.f);
    }
    if (flags & 32) {
      *(float4*)&out[off]     = make_float4(v[0], v[1], v[2], v[3]);
      *(float4*)&out[off + 4] = make_float4(v[4], v[5], v[6], v[7]);
    }
    if (flags & 16) {
      float dn = d2.x;
      f16x8 h8;
      #pragma unroll
      for (int j = 0; j < 8; ++j) h8[j] = (_Float16)(dn * v[j]);
      *(f16x8*)&hs_out[off] = h8;
    }
  }
}

// ---------------- launch ----------------

extern "C" void kernel_launch(void* const* d_in, const int* in_sizes, int n_in,
                              void* d_out, int out_size, void* d_ws, size_t ws_size,
                              hipStream_t stream) {
  const float* x = (const float*)d_in[0];
  const int* ei = (const int*)d_in[1];
  const float* Ws = (const float*)d_in[2];
  const float* bs = (const float*)d_in[3];
  float* out = (float*)d_out;

  const int N = in_sizes[0] / D;
  const int E = in_sizes[1] / 2;
  const int L = in_sizes[2] / (D * D);
  const int* src = ei;
  const int* dst = ei + E;

  uintptr_t p = (uintptr_t)d_ws;
  auto alloc = [&](size_t bytes) {
    uintptr_t r = p;
    p = (r + bytes + 255) & ~(uintptr_t)255;
    return r;
  };
  float2*    dnr      = (float2*)alloc((size_t)N * 8);
  int*       counts   = (int*)  alloc((size_t)N * 4);
  int*       row_ptr  = (int*)  alloc((size_t)(N + 1) * 4);
  int*       fillp    = (int*)  alloc((size_t)N * 4);
  int*       blksum   = (int*)  alloc((size_t)1024 * 4);
  int*       csr_src  = (int*)  alloc((size_t)E * 4);
  _Float16*  hs_a     = (_Float16*)alloc((size_t)N * D * 2);  // ping
  _Float16*  hs_b     = (_Float16*)alloc((size_t)N * D * 2);  // pong
  _Float16*  init16   = (_Float16*)alloc((size_t)N * D * 2);
  _Float16*  Wf       = (_Float16*)alloc((size_t)L * 4 * 8 * 64 * 8 * 2);

  const int NB = (N + SCAN_CH - 1) / SCAN_CH;

  hipMemsetAsync(counts, 0, (size_t)N * 4, stream);
  hist_kernel<<<8 * 192, 256, 0, stream>>>(dst, counts, E, N);
  dis_kernel<<<(N + 255) / 256, 256, 0, stream>>>(counts, dnr, N);
  scan_phaseA<<<NB, 256, 0, stream>>>(counts, blksum, N);
  scan_phaseB<<<1, 1024, 0, stream>>>(blksum, NB);
  scan_phaseC<<<NB, 256, 0, stream>>>(counts, blksum, row_ptr, fillp, N);
  fill_kernel<<<8 * 192, 256, 0, stream>>>(src, dst, fillp, csr_src, E, N);
  conv_x_kernel<<<(N * 16 + 255) / 256, 256, 0, stream>>>(x, dnr, hs_a, init16, N * 16);
  {
    int total = L * 2048;
    repack_w_kernel<<<(total + 255) / 256, 256, 0, stream>>>(Ws, Wf, total);
  }

  const int conv_grid = (N + NPB - 1) / NPB;
  _Float16* hsp[2] = {hs_a, hs_b};
  int cur = 0;

  for (int i = 0; i < L; ++i) {
    int flags;
    if (i == 0)          flags = 4 | 16;
    else if (i == L - 1) flags = 1 | 4 | 32;
    else                 flags = 1 | 2 | 4 | 16;
    conv_fused_kernel<<<conv_grid, CONV_THREADS, 0, stream>>>(hsp[cur], row_ptr, csr_src,
        dnr, (const f16x8*)(Wf + (size_t)i * 2048 * 8), bs + (size_t)i * D,
        init16, init16, out, hsp[cur ^ 1], N, flags);
    if (flags & 16) cur ^= 1;
    if (i < L - 1) {
      int j = (i == 0) ? (L - 1) : (i - 1);
      conv_fused_kernel<<<conv_grid, CONV_THREADS, 0, stream>>>(hsp[cur], row_ptr, csr_src,
          dnr, (const f16x8*)(Wf + (size_t)j * 2048 * 8), bs + (size_t)j * D,
          init16, init16, out, hsp[cur ^ 1], N, 8 | 16);
      cur ^= 1;
    }
  }
}

// Round 15
// 1535.584 us; speedup vs baseline: 1.0303x; 1.0303x over previous
//
#include <hip/hip_runtime.h>

#define D 128
#define SCAN_CH 1024
#define SA_STRIDE 136   // fp16 units; 272B row
#define NPB 64          // nodes per conv block
#define CONV_THREADS 512

typedef _Float16 f16x8 __attribute__((ext_vector_type(8)));
typedef float f32x4 __attribute__((ext_vector_type(4)));

// ---------------- CSR build (XCD-affinity: blockIdx%8 owns dst-range) ----------------

__global__ void hist_kernel(const int* __restrict__ dst, int* __restrict__ counts,
                            int E, int N) {
  int range = blockIdx.x & 7;
  int lo = (int)(((long long)N * range) >> 3);
  int hi = (int)(((long long)N * (range + 1)) >> 3);
  int stride = (gridDim.x >> 3) * blockDim.x;
  for (int e = (blockIdx.x >> 3) * blockDim.x + threadIdx.x; e < E; e += stride) {
    int d = dst[e];
    if (d >= lo && d < hi) atomicAdd(&counts[d], 1);
  }
}

__global__ void fill_kernel(const int* __restrict__ src, const int* __restrict__ dst,
    int* __restrict__ fillp, int* __restrict__ csr_src, int E, int N) {
  int range = blockIdx.x & 7;
  int lo = (int)(((long long)N * range) >> 3);
  int hi = (int)(((long long)N * (range + 1)) >> 3);
  int stride = (gridDim.x >> 3) * blockDim.x;
  for (int e = (blockIdx.x >> 3) * blockDim.x + threadIdx.x; e < E; e += stride) {
    int d = dst[e];
    if (d >= lo && d < hi) {
      int s = src[e];
      int p = atomicAdd(&fillp[d], 1);
      csr_src[p] = s;
    }
  }
}

// dnr[n] = (dn = 1/sqrt(deg+1), rdn = sqrt(deg+1))
__global__ void dis_kernel(const int* __restrict__ counts, float2* __restrict__ dnr, int N) {
  int n = blockIdx.x * blockDim.x + threadIdx.x;
  if (n < N) {
    float c = (float)counts[n] + 1.0f;
    dnr[n] = make_float2(rsqrtf(c), sqrtf(c));
  }
}

__global__ __launch_bounds__(256) void scan_phaseA(const int* __restrict__ counts,
    int* __restrict__ blksum, int N) {
  __shared__ int red[256];
  int base = blockIdx.x * SCAN_CH;
  int t = threadIdx.x;
  int s = 0;
  #pragma unroll
  for (int j = 0; j < 4; ++j) {
    int idx = base + t * 4 + j;
    if (idx < N) s += counts[idx];
  }
  red[t] = s;
  __syncthreads();
  for (int d = 128; d > 0; d >>= 1) {
    if (t < d) red[t] += red[t + d];
    __syncthreads();
  }
  if (t == 0) blksum[blockIdx.x] = red[0];
}

__global__ __launch_bounds__(1024) void scan_phaseB(int* __restrict__ blksum, int NB) {
  __shared__ int sa[1024], sb[1024];
  int t = threadIdx.x;
  int v = (t < NB) ? blksum[t] : 0;
  sa[t] = v;
  __syncthreads();
  int* a = sa; int* b = sb;
  for (int d = 1; d < 1024; d <<= 1) {
    int val = a[t] + ((t >= d) ? a[t - d] : 0);
    b[t] = val;
    __syncthreads();
    int* tmp = a; a = b; b = tmp;
  }
  if (t < NB) blksum[t] = a[t] - v;  // exclusive
}

__global__ __launch_bounds__(256) void scan_phaseC(const int* __restrict__ counts,
    const int* __restrict__ blksum, int* __restrict__ row_ptr, int* __restrict__ fillp, int N) {
  __shared__ int ra[256], rb[256];
  int base = blockIdx.x * SCAN_CH;
  int t = threadIdx.x;
  int v[4]; int s = 0;
  #pragma unroll
  for (int j = 0; j < 4; ++j) {
    int idx = base + t * 4 + j;
    v[j] = (idx < N) ? counts[idx] : 0;
    s += v[j];
  }
  ra[t] = s;
  __syncthreads();
  int* a = ra; int* b = rb;
  for (int d = 1; d < 256; d <<= 1) {
    int val = a[t] + ((t >= d) ? a[t - d] : 0);
    b[t] = val;
    __syncthreads();
    int* tmp = a; a = b; b = tmp;
  }
  int excl = a[t] - s + blksum[blockIdx.x];
  #pragma unroll
  for (int j = 0; j < 4; ++j) {
    int idx = base + t * 4 + j;
    if (idx < N) {
      row_ptr[idx] = excl;
      fillp[idx] = excl;
      excl += v[j];
      if (idx == N - 1) row_ptr[N] = excl;
    }
  }
}

// ---------------- one-time conversions ----------------

// hs0 = dn * x[n] (fp16 gather table); x16 = fp16(x) (residual stream seed)
__global__ void conv_x_kernel(const float* __restrict__ x, const float2* __restrict__ dnr,
    _Float16* __restrict__ hs, _Float16* __restrict__ x16, int total8) {
  int i = blockIdx.x * blockDim.x + threadIdx.x;
  if (i >= total8) return;
  int node = i >> 4;
  float dn = dnr[node].x;
  const float4* p = (const float4*)(x + (size_t)i * 8);
  float4 a = p[0], b = p[1];
  f16x8 v, w;
  v[0] = (_Float16)(dn * a.x); v[1] = (_Float16)(dn * a.y);
  v[2] = (_Float16)(dn * a.z); v[3] = (_Float16)(dn * a.w);
  v[4] = (_Float16)(dn * b.x); v[5] = (_Float16)(dn * b.y);
  v[6] = (_Float16)(dn * b.z); v[7] = (_Float16)(dn * b.w);
  w[0] = (_Float16)a.x; w[1] = (_Float16)a.y; w[2] = (_Float16)a.z; w[3] = (_Float16)a.w;
  w[4] = (_Float16)b.x; w[5] = (_Float16)b.y; w[6] = (_Float16)b.z; w[7] = (_Float16)b.w;
  *(f16x8*)(hs + (size_t)i * 8) = v;
  *(f16x8*)(x16 + (size_t)i * 8) = w;
}

// Wf layout: [L][kb(4)][nb(8)][lane(64)] of f16x8 (B fragment, K-slice 8)
__global__ void repack_w_kernel(const float* __restrict__ Ws, _Float16* __restrict__ Wf, int total) {
  int t = blockIdx.x * blockDim.x + threadIdx.x;
  if (t >= total) return;
  int lane = t & 63;
  int nb = (t >> 6) & 7;
  int kb = (t >> 9) & 3;
  int l = t >> 11;
  int col = nb * 16 + (lane & 15);
  int k0 = kb * 32 + (lane >> 4) * 8;
  const float* w = Ws + (size_t)l * D * D;
  f16x8 v;
  #pragma unroll
  for (int j = 0; j < 8; ++j) v[j] = (_Float16)w[(k0 + j) * D + col];
  *(f16x8*)(Wf + (size_t)t * 8) = v;
}

// ---------------- Fused conv ----------------
// conv_n = [dn*(sum_e hs[src_e] + hs[n])] @ W + b   (self-loop in gather)
// Single barrier; epilogue runs in MFMA C-fragment layout (no LDS transpose,
// no bank conflicts). row = rt*16+(lane>>4)*4+r, col = wave*16+(lane&15).
// flags: 1=+init16in, 2=write init16out, 4=relu, 8=+h (hs[n]*rdn), 16=write hs_out,
//        32=write out (fp32 final)
__global__ __launch_bounds__(CONV_THREADS) void conv_fused_kernel(
    const _Float16* __restrict__ hs, const int* __restrict__ row_ptr,
    const int* __restrict__ csr_src, const float2* __restrict__ dnr,
    const f16x8* __restrict__ Wf, const float* __restrict__ bias,
    const _Float16* __restrict__ init16in, _Float16* __restrict__ init16out,
    float* __restrict__ out, _Float16* __restrict__ hs_out, int N, int flags) {
  __shared__ _Float16 sA[NPB * SA_STRIDE];   // 17.4 KB
  int tid = threadIdx.x;
  int node0 = blockIdx.x * NPB;
  int ng = tid >> 4;          // 0..31 group of 16 lanes
  int li = tid & 15;
  int c0 = li * 8;
  int wave = tid >> 6, lane = tid & 63;

  // ---- B fragments first: in flight under the gather ----
  f16x8 bf[4];
  #pragma unroll
  for (int kb = 0; kb < 4; ++kb)
    bf[kb] = Wf[(kb * 8 + wave) * 64 + lane];

  // ---- gather: each 16-lane group handles 2 nodes sequentially ----
  #pragma unroll
  for (int k = 0; k < 2; ++k) {
    int lr = ng + 32 * k;
    int n = node0 + lr;
    f16x8 g = {};
    if (n < N) {
      float acc[8];
      #pragma unroll
      for (int j = 0; j < 8; ++j) acc[j] = 0.f;
      int beg = row_ptr[n], end = row_ptr[n + 1];
      #pragma unroll 4
      for (int e = beg; e < end; ++e) {
        int s = csr_src[e];
        f16x8 v = *(const f16x8*)&hs[(size_t)s * D + c0];
        #pragma unroll
        for (int j = 0; j < 8; ++j) acc[j] += (float)v[j];
      }
      f16x8 own = *(const f16x8*)&hs[(size_t)n * D + c0];
      float dn = dnr[n].x;
      #pragma unroll
      for (int j = 0; j < 8; ++j) g[j] = (_Float16)(dn * (acc[j] + (float)own[j]));
    }
    *(f16x8*)&sA[lr * SA_STRIDE + c0] = g;
  }
  __syncthreads();   // the ONLY barrier

  // ---- MFMA: 64x128 A (4 row-tiles) x per-wave 16 cols ----
  f32x4 ca[4];
  #pragma unroll
  for (int rt = 0; rt < 4; ++rt) ca[rt] = (f32x4){0, 0, 0, 0};
  #pragma unroll
  for (int rt = 0; rt < 4; ++rt) {
    #pragma unroll
    for (int kb = 0; kb < 4; ++kb) {
      f16x8 a = *(const f16x8*)&sA[(rt * 16 + (lane & 15)) * SA_STRIDE + kb * 32 + (lane >> 4) * 8];
      ca[rt] = __builtin_amdgcn_mfma_f32_16x16x32_f16(a, bf[kb], ca[rt], 0, 0, 0);
    }
  }

  // ---- epilogue in C-fragment layout (elementwise; no LDS) ----
  int colb = wave * 16 + (lane & 15);
  float bcol = bias[colb];
  int rbase = (lane >> 4) * 4;
  #pragma unroll
  for (int rt = 0; rt < 4; ++rt) {
    #pragma unroll
    for (int r = 0; r < 4; ++r) {
      int lr = rt * 16 + rbase + r;
      int n = node0 + lr;
      if (n >= N) continue;
      float v = ca[rt][r] + bcol;
      size_t off = (size_t)n * D + colb;
      float2 d2 = dnr[n];
      if (flags & 8)  v += (float)hs[off] * d2.y;       // h-add: hs_own * rdn
      if (flags & 1)  v += (float)init16in[off];
      if (flags & 2)  init16out[off] = (_Float16)v;
      if (flags & 4)  v = fmaxf(v, 0.f);
      if (flags & 32) out[off] = v;
      if (flags & 16) hs_out[off] = (_Float16)(d2.x * v);
    }
  }
}

// ---------------- launch ----------------

extern "C" void kernel_launch(void* const* d_in, const int* in_sizes, int n_in,
                              void* d_out, int out_size, void* d_ws, size_t ws_size,
                              hipStream_t stream) {
  const float* x = (const float*)d_in[0];
  const int* ei = (const int*)d_in[1];
  const float* Ws = (const float*)d_in[2];
  const float* bs = (const float*)d_in[3];
  float* out = (float*)d_out;

  const int N = in_sizes[0] / D;
  const int E = in_sizes[1] / 2;
  const int L = in_sizes[2] / (D * D);
  const int* src = ei;
  const int* dst = ei + E;

  uintptr_t p = (uintptr_t)d_ws;
  auto alloc = [&](size_t bytes) {
    uintptr_t r = p;
    p = (r + bytes + 255) & ~(uintptr_t)255;
    return r;
  };
  float2*    dnr      = (float2*)alloc((size_t)N * 8);
  int*       counts   = (int*)  alloc((size_t)N * 4);
  int*       row_ptr  = (int*)  alloc((size_t)(N + 1) * 4);
  int*       fillp    = (int*)  alloc((size_t)N * 4);
  int*       blksum   = (int*)  alloc((size_t)1024 * 4);
  int*       csr_src  = (int*)  alloc((size_t)E * 4);
  _Float16*  hs_a     = (_Float16*)alloc((size_t)N * D * 2);  // ping
  _Float16*  hs_b     = (_Float16*)alloc((size_t)N * D * 2);  // pong
  _Float16*  init16   = (_Float16*)alloc((size_t)N * D * 2);
  _Float16*  Wf       = (_Float16*)alloc((size_t)L * 4 * 8 * 64 * 8 * 2);

  const int NB = (N + SCAN_CH - 1) / SCAN_CH;

  hipMemsetAsync(counts, 0, (size_t)N * 4, stream);
  hist_kernel<<<8 * 192, 256, 0, stream>>>(dst, counts, E, N);
  dis_kernel<<<(N + 255) / 256, 256, 0, stream>>>(counts, dnr, N);
  scan_phaseA<<<NB, 256, 0, stream>>>(counts, blksum, N);
  scan_phaseB<<<1, 1024, 0, stream>>>(blksum, NB);
  scan_phaseC<<<NB, 256, 0, stream>>>(counts, blksum, row_ptr, fillp, N);
  fill_kernel<<<8 * 192, 256, 0, stream>>>(src, dst, fillp, csr_src, E, N);
  conv_x_kernel<<<(N * 16 + 255) / 256, 256, 0, stream>>>(x, dnr, hs_a, init16, N * 16);
  {
    int total = L * 2048;
    repack_w_kernel<<<(total + 255) / 256, 256, 0, stream>>>(Ws, Wf, total);
  }

  const int conv_grid = (N + NPB - 1) / NPB;
  _Float16* hsp[2] = {hs_a, hs_b};
  int cur = 0;

  for (int i = 0; i < L; ++i) {
    int flags;
    if (i == 0)          flags = 4 | 16;
    else if (i == L - 1) flags = 1 | 4 | 32;
    else                 flags = 1 | 2 | 4 | 16;
    conv_fused_kernel<<<conv_grid, CONV_THREADS, 0, stream>>>(hsp[cur], row_ptr, csr_src,
        dnr, (const f16x8*)(Wf + (size_t)i * 2048 * 8), bs + (size_t)i * D,
        init16, init16, out, hsp[cur ^ 1], N, flags);
    if (flags & 16) cur ^= 1;
    if (i < L - 1) {
      int j = (i == 0) ? (L - 1) : (i - 1);
      conv_fused_kernel<<<conv_grid, CONV_THREADS, 0, stream>>>(hsp[cur], row_ptr, csr_src,
          dnr, (const f16x8*)(Wf + (size_t)j * 2048 * 8), bs + (size_t)j * D,
          init16, init16, out, hsp[cur ^ 1], N, 8 | 16);
      cur ^= 1;
    }
  }
}

// Round 16
// 1358.370 us; speedup vs baseline: 1.1647x; 1.1305x over previous
//
#include <hip/hip_runtime.h>

#define D 128
#define SCAN_CH 1024
#define SA_STRIDE 136   // fp16 units; 272B row
#define SC_STRIDE 132   // fp32 units; 528B row
#define NPB 64          // nodes per conv block
#define CONV_THREADS 512

typedef _Float16 f16x8 __attribute__((ext_vector_type(8)));
typedef float f32x4 __attribute__((ext_vector_type(4)));

// ---------------- CSR build (XCD-affinity: blockIdx%8 owns dst-range) ----------------

__global__ void hist_kernel(const int* __restrict__ dst, int* __restrict__ counts,
                            int E, int N) {
  int range = blockIdx.x & 7;
  int lo = (int)(((long long)N * range) >> 3);
  int hi = (int)(((long long)N * (range + 1)) >> 3);
  int stride = (gridDim.x >> 3) * blockDim.x;
  for (int e = (blockIdx.x >> 3) * blockDim.x + threadIdx.x; e < E; e += stride) {
    int d = dst[e];
    if (d >= lo && d < hi) atomicAdd(&counts[d], 1);
  }
}

__global__ void fill_kernel(const int* __restrict__ src, const int* __restrict__ dst,
    int* __restrict__ fillp, int* __restrict__ csr_src, int E, int N) {
  int range = blockIdx.x & 7;
  int lo = (int)(((long long)N * range) >> 3);
  int hi = (int)(((long long)N * (range + 1)) >> 3);
  int stride = (gridDim.x >> 3) * blockDim.x;
  for (int e = (blockIdx.x >> 3) * blockDim.x + threadIdx.x; e < E; e += stride) {
    int d = dst[e];
    if (d >= lo && d < hi) {
      int s = src[e];
      int p = atomicAdd(&fillp[d], 1);
      csr_src[p] = s;
    }
  }
}

// dnr[n] = (dn = 1/sqrt(deg+1), rdn = sqrt(deg+1))
__global__ void dis_kernel(const int* __restrict__ counts, float2* __restrict__ dnr, int N) {
  int n = blockIdx.x * blockDim.x + threadIdx.x;
  if (n < N) {
    float c = (float)counts[n] + 1.0f;
    dnr[n] = make_float2(rsqrtf(c), sqrtf(c));
  }
}

__global__ __launch_bounds__(256) void scan_phaseA(const int* __restrict__ counts,
    int* __restrict__ blksum, int N) {
  __shared__ int red[256];
  int base = blockIdx.x * SCAN_CH;
  int t = threadIdx.x;
  int s = 0;
  #pragma unroll
  for (int j = 0; j < 4; ++j) {
    int idx = base + t * 4 + j;
    if (idx < N) s += counts[idx];
  }
  red[t] = s;
  __syncthreads();
  for (int d = 128; d > 0; d >>= 1) {
    if (t < d) red[t] += red[t + d];
    __syncthreads();
  }
  if (t == 0) blksum[blockIdx.x] = red[0];
}

__global__ __launch_bounds__(1024) void scan_phaseB(int* __restrict__ blksum, int NB) {
  __shared__ int sa[1024], sb[1024];
  int t = threadIdx.x;
  int v = (t < NB) ? blksum[t] : 0;
  sa[t] = v;
  __syncthreads();
  int* a = sa; int* b = sb;
  for (int d = 1; d < 1024; d <<= 1) {
    int val = a[t] + ((t >= d) ? a[t - d] : 0);
    b[t] = val;
    __syncthreads();
    int* tmp = a; a = b; b = tmp;
  }
  if (t < NB) blksum[t] = a[t] - v;  // exclusive
}

__global__ __launch_bounds__(256) void scan_phaseC(const int* __restrict__ counts,
    const int* __restrict__ blksum, int* __restrict__ row_ptr, int* __restrict__ fillp, int N) {
  __shared__ int ra[256], rb[256];
  int base = blockIdx.x * SCAN_CH;
  int t = threadIdx.x;
  int v[4]; int s = 0;
  #pragma unroll
  for (int j = 0; j < 4; ++j) {
    int idx = base + t * 4 + j;
    v[j] = (idx < N) ? counts[idx] : 0;
    s += v[j];
  }
  ra[t] = s;
  __syncthreads();
  int* a = ra; int* b = rb;
  for (int d = 1; d < 256; d <<= 1) {
    int val = a[t] + ((t >= d) ? a[t - d] : 0);
    b[t] = val;
    __syncthreads();
    int* tmp = a; a = b; b = tmp;
  }
  int excl = a[t] - s + blksum[blockIdx.x];
  #pragma unroll
  for (int j = 0; j < 4; ++j) {
    int idx = base + t * 4 + j;
    if (idx < N) {
      row_ptr[idx] = excl;
      fillp[idx] = excl;
      excl += v[j];
      if (idx == N - 1) row_ptr[N] = excl;
    }
  }
}

// ---------------- one-time conversions ----------------

// hs0 = dn * x[n] (fp16 gather table); x16 = fp16(x) (residual stream seed)
__global__ void conv_x_kernel(const float* __restrict__ x, const float2* __restrict__ dnr,
    _Float16* __restrict__ hs, _Float16* __restrict__ x16, int total8) {
  int i = blockIdx.x * blockDim.x + threadIdx.x;
  if (i >= total8) return;
  int node = i >> 4;
  float dn = dnr[node].x;
  const float4* p = (const float4*)(x + (size_t)i * 8);
  float4 a = p[0], b = p[1];
  f16x8 v, w;
  v[0] = (_Float16)(dn * a.x); v[1] = (_Float16)(dn * a.y);
  v[2] = (_Float16)(dn * a.z); v[3] = (_Float16)(dn * a.w);
  v[4] = (_Float16)(dn * b.x); v[5] = (_Float16)(dn * b.y);
  v[6] = (_Float16)(dn * b.z); v[7] = (_Float16)(dn * b.w);
  w[0] = (_Float16)a.x; w[1] = (_Float16)a.y; w[2] = (_Float16)a.z; w[3] = (_Float16)a.w;
  w[4] = (_Float16)b.x; w[5] = (_Float16)b.y; w[6] = (_Float16)b.z; w[7] = (_Float16)b.w;
  *(f16x8*)(hs + (size_t)i * 8) = v;
  *(f16x8*)(x16 + (size_t)i * 8) = w;
}

// Wf layout: [L][kb(4)][nb(8)][lane(64)] of f16x8 (B fragment, K-slice 8)
__global__ void repack_w_kernel(const float* __restrict__ Ws, _Float16* __restrict__ Wf, int total) {
  int t = blockIdx.x * blockDim.x + threadIdx.x;
  if (t >= total) return;
  int lane = t & 63;
  int nb = (t >> 6) & 7;
  int kb = (t >> 9) & 3;
  int l = t >> 11;
  int col = nb * 16 + (lane & 15);
  int k0 = kb * 32 + (lane >> 4) * 8;
  const float* w = Ws + (size_t)l * D * D;
  f16x8 v;
  #pragma unroll
  for (int j = 0; j < 8; ++j) v[j] = (_Float16)w[(k0 + j) * D + col];
  *(f16x8*)(Wf + (size_t)t * 8) = v;
}

// ---------------- Fused conv ----------------
// conv_n = [dn*(sum_e hs[src_e] + hs[n])] @ W + b   (self-loop in gather)
// Proven best body (r10): 16-lane groups, gather unroll 4, sA/sC aliased LDS,
// coalesced row-major epilogue.
// flags: 1=+init16in, 2=write init16out, 4=relu, 8=+h (ownr*rdn), 16=write hs_out,
//        32=write out (fp32 final)
__global__ __launch_bounds__(CONV_THREADS) void conv_fused_kernel(
    const _Float16* __restrict__ hs, const int* __restrict__ row_ptr,
    const int* __restrict__ csr_src, const float2* __restrict__ dnr,
    const f16x8* __restrict__ Wf, const float* __restrict__ bias,
    const _Float16* __restrict__ init16in, _Float16* __restrict__ init16out,
    float* __restrict__ out, _Float16* __restrict__ hs_out, int N, int flags) {
  __shared__ __align__(16) char smem[NPB * SC_STRIDE * 4];  // sA and sC alias
  _Float16* sA = (_Float16*)smem;
  float* sC = (float*)smem;
  int tid = threadIdx.x;
  int node0 = blockIdx.x * NPB;
  int ng = tid >> 4;          // 0..31 group of 16 lanes
  int li = tid & 15;
  int c0 = li * 8;
  int wave = tid >> 6, lane = tid & 63;

  // ---- B fragments first: in flight under the gather ----
  f16x8 bf[4];
  #pragma unroll
  for (int kb = 0; kb < 4; ++kb)
    bf[kb] = Wf[(kb * 8 + wave) * 64 + lane];

  float2 dr[2];
  f16x8 ownr[2];

  // ---- gather: each 16-lane group handles 2 nodes sequentially ----
  #pragma unroll
  for (int k = 0; k < 2; ++k) {
    int lr = ng + 32 * k;
    int n = node0 + lr;
    f16x8 g = {};
    if (n < N) {
      float acc[8];
      #pragma unroll
      for (int j = 0; j < 8; ++j) acc[j] = 0.f;
      int beg = row_ptr[n], end = row_ptr[n + 1];
      #pragma unroll 4
      for (int e = beg; e < end; ++e) {
        int s = csr_src[e];
        f16x8 v = *(const f16x8*)&hs[(size_t)s * D + c0];
        #pragma unroll
        for (int j = 0; j < 8; ++j) acc[j] += (float)v[j];
      }
      f16x8 own = *(const f16x8*)&hs[(size_t)n * D + c0];
      float2 d2 = dnr[n];
      dr[k] = d2;
      ownr[k] = own;
      #pragma unroll
      for (int j = 0; j < 8; ++j) g[j] = (_Float16)(d2.x * (acc[j] + (float)own[j]));
    }
    *(f16x8*)&sA[lr * SA_STRIDE + c0] = g;
  }
  __syncthreads();

  // ---- MFMA: 64x128 A (4 row-tiles) x per-wave 16 cols ----
  f32x4 ca[4];
  #pragma unroll
  for (int rt = 0; rt < 4; ++rt) ca[rt] = (f32x4){0, 0, 0, 0};
  #pragma unroll
  for (int rt = 0; rt < 4; ++rt) {
    #pragma unroll
    for (int kb = 0; kb < 4; ++kb) {
      f16x8 a = *(const f16x8*)&sA[(rt * 16 + (lane & 15)) * SA_STRIDE + kb * 32 + (lane >> 4) * 8];
      ca[rt] = __builtin_amdgcn_mfma_f32_16x16x32_f16(a, bf[kb], ca[rt], 0, 0, 0);
    }
  }
  __syncthreads();   // all sA reads done before sC overwrites the same LDS

  // ---- stage C ----
  {
    int colb = wave * 16 + (lane & 15);
    int rowb = (lane >> 4) * 4;
    #pragma unroll
    for (int rt = 0; rt < 4; ++rt)
      #pragma unroll
      for (int r = 0; r < 4; ++r)
        sC[(rt * 16 + rowb + r) * SC_STRIDE + colb] = ca[rt][r];
  }
  __syncthreads();

  // ---- epilogue: 2 passes of 32 nodes; thread handles 8 features ----
  float4 b0 = *(const float4*)&bias[c0];
  float4 b1 = *(const float4*)&bias[c0 + 4];
  #pragma unroll
  for (int k = 0; k < 2; ++k) {
    int lr = ng + 32 * k;
    int n = node0 + lr;
    if (n >= N) continue;
    float v[8];
    float4 s0 = *(const float4*)&sC[lr * SC_STRIDE + c0];
    float4 s1 = *(const float4*)&sC[lr * SC_STRIDE + c0 + 4];
    v[0] = s0.x + b0.x; v[1] = s0.y + b0.y; v[2] = s0.z + b0.z; v[3] = s0.w + b0.w;
    v[4] = s1.x + b1.x; v[5] = s1.y + b1.y; v[6] = s1.z + b1.z; v[7] = s1.w + b1.w;
    size_t off = (size_t)n * D + c0;
    if (flags & 8) {     // h-add: h = hs_own * rdn (no global read)
      float rd = dr[k].y;
      #pragma unroll
      for (int j = 0; j < 8; ++j) v[j] += (float)ownr[k][j] * rd;
    }
    if (flags & 1) {
      f16x8 iv = *(const f16x8*)&init16in[off];
      #pragma unroll
      for (int j = 0; j < 8; ++j) v[j] += (float)iv[j];
    }
    if (flags & 2) {
      f16x8 o;
      #pragma unroll
      for (int j = 0; j < 8; ++j) o[j] = (_Float16)v[j];
      *(f16x8*)&init16out[off] = o;
    }
    if (flags & 4) {
      #pragma unroll
      for (int j = 0; j < 8; ++j) v[j] = fmaxf(v[j], 0.f);
    }
    if (flags & 32) {
      *(float4*)&out[off]     = make_float4(v[0], v[1], v[2], v[3]);
      *(float4*)&out[off + 4] = make_float4(v[4], v[5], v[6], v[7]);
    }
    if (flags & 16) {
      float dn = dr[k].x;
      f16x8 h8;
      #pragma unroll
      for (int j = 0; j < 8; ++j) h8[j] = (_Float16)(dn * v[j]);
      *(f16x8*)&hs_out[off] = h8;
    }
  }
}

// ---------------- launch ----------------

extern "C" void kernel_launch(void* const* d_in, const int* in_sizes, int n_in,
                              void* d_out, int out_size, void* d_ws, size_t ws_size,
                              hipStream_t stream) {
  const float* x = (const float*)d_in[0];
  const int* ei = (const int*)d_in[1];
  const float* Ws = (const float*)d_in[2];
  const float* bs = (const float*)d_in[3];
  float* out = (float*)d_out;

  const int N = in_sizes[0] / D;
  const int E = in_sizes[1] / 2;
  const int L = in_sizes[2] / (D * D);
  const int* src = ei;
  const int* dst = ei + E;

  uintptr_t p = (uintptr_t)d_ws;
  auto alloc = [&](size_t bytes) {
    uintptr_t r = p;
    p = (r + bytes + 255) & ~(uintptr_t)255;
    return r;
  };
  float2*    dnr      = (float2*)alloc((size_t)N * 8);
  int*       counts   = (int*)  alloc((size_t)N * 4);
  int*       row_ptr  = (int*)  alloc((size_t)(N + 1) * 4);
  int*       fillp    = (int*)  alloc((size_t)N * 4);
  int*       blksum   = (int*)  alloc((size_t)1024 * 4);
  int*       csr_src  = (int*)  alloc((size_t)E * 4);
  _Float16*  hs_a     = (_Float16*)alloc((size_t)N * D * 2);  // ping
  _Float16*  hs_b     = (_Float16*)alloc((size_t)N * D * 2);  // pong
  _Float16*  init16   = (_Float16*)alloc((size_t)N * D * 2);
  _Float16*  Wf       = (_Float16*)alloc((size_t)L * 4 * 8 * 64 * 8 * 2);

  const int NB = (N + SCAN_CH - 1) / SCAN_CH;

  hipMemsetAsync(counts, 0, (size_t)N * 4, stream);
  hist_kernel<<<8 * 192, 256, 0, stream>>>(dst, counts, E, N);
  dis_kernel<<<(N + 255) / 256, 256, 0, stream>>>(counts, dnr, N);
  scan_phaseA<<<NB, 256, 0, stream>>>(counts, blksum, N);
  scan_phaseB<<<1, 1024, 0, stream>>>(blksum, NB);
  scan_phaseC<<<NB, 256, 0, stream>>>(counts, blksum, row_ptr, fillp, N);
  fill_kernel<<<8 * 192, 256, 0, stream>>>(src, dst, fillp, csr_src, E, N);
  conv_x_kernel<<<(N * 16 + 255) / 256, 256, 0, stream>>>(x, dnr, hs_a, init16, N * 16);
  {
    int total = L * 2048;
    repack_w_kernel<<<(total + 255) / 256, 256, 0, stream>>>(Ws, Wf, total);
  }

  const int conv_grid = (N + NPB - 1) / NPB;
  _Float16* hsp[2] = {hs_a, hs_b};
  int cur = 0;

  for (int i = 0; i < L; ++i) {
    int flags;
    if (i == 0)          flags = 4 | 16;
    else if (i == L - 1) flags = 1 | 4 | 32;
    else                 flags = 1 | 2 | 4 | 16;
    conv_fused_kernel<<<conv_grid, CONV_THREADS, 0, stream>>>(hsp[cur], row_ptr, csr_src,
        dnr, (const f16x8*)(Wf + (size_t)i * 2048 * 8), bs + (size_t)i * D,
        init16, init16, out, hsp[cur ^ 1], N, flags);
    if (flags & 16) cur ^= 1;
    if (i < L - 1) {
      int j = (i == 0) ? (L - 1) : (i - 1);
      conv_fused_kernel<<<conv_grid, CONV_THREADS, 0, stream>>>(hsp[cur], row_ptr, csr_src,
          dnr, (const f16x8*)(Wf + (size_t)j * 2048 * 8), bs + (size_t)j * D,
          init16, init16, out, hsp[cur ^ 1], N, 8 | 16);
      cur ^= 1;
    }
  }
}

// Round 17
// 1268.977 us; speedup vs baseline: 1.2468x; 1.0704x over previous
//
#include <hip/hip_runtime.h>

#define D 128
#define SCAN_CH 1024
#define SA_STRIDE 136   // fp16 units; 272B row
#define SC_STRIDE 132   // fp32 units; 528B row
#define NPB 64          // nodes per conv block
#define CONV_THREADS 512

typedef _Float16 f16x8 __attribute__((ext_vector_type(8)));
typedef float f32x4 __attribute__((ext_vector_type(4)));

// ---------------- CSR build (XCD-affinity: blockIdx%8 owns dst-range) ----------------

__global__ void hist_kernel(const int* __restrict__ dst, int* __restrict__ counts,
                            int E, int N) {
  int range = blockIdx.x & 7;
  int lo = (int)(((long long)N * range) >> 3);
  int hi = (int)(((long long)N * (range + 1)) >> 3);
  int stride = (gridDim.x >> 3) * blockDim.x;
  for (int e = (blockIdx.x >> 3) * blockDim.x + threadIdx.x; e < E; e += stride) {
    int d = dst[e];
    if (d >= lo && d < hi) atomicAdd(&counts[d], 1);
  }
}

__global__ void fill_kernel(const int* __restrict__ src, const int* __restrict__ dst,
    int* __restrict__ fillp, int* __restrict__ csr_src, int E, int N) {
  int range = blockIdx.x & 7;
  int lo = (int)(((long long)N * range) >> 3);
  int hi = (int)(((long long)N * (range + 1)) >> 3);
  int stride = (gridDim.x >> 3) * blockDim.x;
  for (int e = (blockIdx.x >> 3) * blockDim.x + threadIdx.x; e < E; e += stride) {
    int d = dst[e];
    if (d >= lo && d < hi) {
      int s = src[e];
      int p = atomicAdd(&fillp[d], 1);
      csr_src[p] = s;
    }
  }
}

// dnr[n] = (dn = 1/sqrt(deg+1), rdn = sqrt(deg+1))
__global__ void dis_kernel(const int* __restrict__ counts, float2* __restrict__ dnr, int N) {
  int n = blockIdx.x * blockDim.x + threadIdx.x;
  if (n < N) {
    float c = (float)counts[n] + 1.0f;
    dnr[n] = make_float2(rsqrtf(c), sqrtf(c));
  }
}

__global__ __launch_bounds__(256) void scan_phaseA(const int* __restrict__ counts,
    int* __restrict__ blksum, int N) {
  __shared__ int red[256];
  int base = blockIdx.x * SCAN_CH;
  int t = threadIdx.x;
  int s = 0;
  #pragma unroll
  for (int j = 0; j < 4; ++j) {
    int idx = base + t * 4 + j;
    if (idx < N) s += counts[idx];
  }
  red[t] = s;
  __syncthreads();
  for (int d = 128; d > 0; d >>= 1) {
    if (t < d) red[t] += red[t + d];
    __syncthreads();
  }
  if (t == 0) blksum[blockIdx.x] = red[0];
}

__global__ __launch_bounds__(1024) void scan_phaseB(int* __restrict__ blksum, int NB) {
  __shared__ int sa[1024], sb[1024];
  int t = threadIdx.x;
  int v = (t < NB) ? blksum[t] : 0;
  sa[t] = v;
  __syncthreads();
  int* a = sa; int* b = sb;
  for (int d = 1; d < 1024; d <<= 1) {
    int val = a[t] + ((t >= d) ? a[t - d] : 0);
    b[t] = val;
    __syncthreads();
    int* tmp = a; a = b; b = tmp;
  }
  if (t < NB) blksum[t] = a[t] - v;  // exclusive
}

__global__ __launch_bounds__(256) void scan_phaseC(const int* __restrict__ counts,
    const int* __restrict__ blksum, int* __restrict__ row_ptr, int* __restrict__ fillp, int N) {
  __shared__ int ra[256], rb[256];
  int base = blockIdx.x * SCAN_CH;
  int t = threadIdx.x;
  int v[4]; int s = 0;
  #pragma unroll
  for (int j = 0; j < 4; ++j) {
    int idx = base + t * 4 + j;
    v[j] = (idx < N) ? counts[idx] : 0;
    s += v[j];
  }
  ra[t] = s;
  __syncthreads();
  int* a = ra; int* b = rb;
  for (int d = 1; d < 256; d <<= 1) {
    int val = a[t] + ((t >= d) ? a[t - d] : 0);
    b[t] = val;
    __syncthreads();
    int* tmp = a; a = b; b = tmp;
  }
  int excl = a[t] - s + blksum[blockIdx.x];
  #pragma unroll
  for (int j = 0; j < 4; ++j) {
    int idx = base + t * 4 + j;
    if (idx < N) {
      row_ptr[idx] = excl;
      fillp[idx] = excl;
      excl += v[j];
      if (idx == N - 1) row_ptr[N] = excl;
    }
  }
}

// ---------------- one-time conversions ----------------

// hs0 = dn * x[n] (fp16 gather table); x16 = fp16(x) (residual stream seed)
__global__ void conv_x_kernel(const float* __restrict__ x, const float2* __restrict__ dnr,
    _Float16* __restrict__ hs, _Float16* __restrict__ x16, int total8) {
  int i = blockIdx.x * blockDim.x + threadIdx.x;
  if (i >= total8) return;
  int node = i >> 4;
  float dn = dnr[node].x;
  const float4* p = (const float4*)(x + (size_t)i * 8);
  float4 a = p[0], b = p[1];
  f16x8 v, w;
  v[0] = (_Float16)(dn * a.x); v[1] = (_Float16)(dn * a.y);
  v[2] = (_Float16)(dn * a.z); v[3] = (_Float16)(dn * a.w);
  v[4] = (_Float16)(dn * b.x); v[5] = (_Float16)(dn * b.y);
  v[6] = (_Float16)(dn * b.z); v[7] = (_Float16)(dn * b.w);
  w[0] = (_Float16)a.x; w[1] = (_Float16)a.y; w[2] = (_Float16)a.z; w[3] = (_Float16)a.w;
  w[4] = (_Float16)b.x; w[5] = (_Float16)b.y; w[6] = (_Float16)b.z; w[7] = (_Float16)b.w;
  *(f16x8*)(hs + (size_t)i * 8) = v;
  *(f16x8*)(x16 + (size_t)i * 8) = w;
}

// Wf layout: [L][kb(4)][nb(8)][lane(64)] of f16x8 (B fragment, K-slice 8)
__global__ void repack_w_kernel(const float* __restrict__ Ws, _Float16* __restrict__ Wf, int total) {
  int t = blockIdx.x * blockDim.x + threadIdx.x;
  if (t >= total) return;
  int lane = t & 63;
  int nb = (t >> 6) & 7;
  int kb = (t >> 9) & 3;
  int l = t >> 11;
  int col = nb * 16 + (lane & 15);
  int k0 = kb * 32 + (lane >> 4) * 8;
  const float* w = Ws + (size_t)l * D * D;
  f16x8 v;
  #pragma unroll
  for (int j = 0; j < 8; ++j) v[j] = (_Float16)w[(k0 + j) * D + col];
  *(f16x8*)(Wf + (size_t)t * 8) = v;
}

// ---------------- Fused conv ----------------
// conv_n = [dn*(sum_e hs[src_e] + hs[n])] @ W + b   (self-loop in gather)
// r10 body exactly: 16-lane groups, gather unroll 4, B-frags loaded AFTER the
// gather (hoisting them regressed achieved occupancy 52% -> 35%).
// flags: 1=+init16in, 2=write init16out, 4=relu, 8=+h (ownr*rdn), 16=write hs_out,
//        32=write out (fp32 final)
__global__ __launch_bounds__(CONV_THREADS) void conv_fused_kernel(
    const _Float16* __restrict__ hs, const int* __restrict__ row_ptr,
    const int* __restrict__ csr_src, const float2* __restrict__ dnr,
    const f16x8* __restrict__ Wf, const float* __restrict__ bias,
    const _Float16* __restrict__ init16in, _Float16* __restrict__ init16out,
    float* __restrict__ out, _Float16* __restrict__ hs_out, int N, int flags) {
  __shared__ __align__(16) char smem[NPB * SC_STRIDE * 4];  // sA and sC alias
  _Float16* sA = (_Float16*)smem;
  float* sC = (float*)smem;
  int tid = threadIdx.x;
  int node0 = blockIdx.x * NPB;
  int ng = tid >> 4;          // 0..31 group of 16 lanes
  int li = tid & 15;
  int c0 = li * 8;
  int wave = tid >> 6, lane = tid & 63;

  float2 dr[2];
  f16x8 ownr[2];

  // ---- gather: each 16-lane group handles 2 nodes sequentially ----
  #pragma unroll
  for (int k = 0; k < 2; ++k) {
    int lr = ng + 32 * k;
    int n = node0 + lr;
    f16x8 g = {};
    if (n < N) {
      float acc[8];
      #pragma unroll
      for (int j = 0; j < 8; ++j) acc[j] = 0.f;
      int beg = row_ptr[n], end = row_ptr[n + 1];
      #pragma unroll 4
      for (int e = beg; e < end; ++e) {
        int s = csr_src[e];
        f16x8 v = *(const f16x8*)&hs[(size_t)s * D + c0];
        #pragma unroll
        for (int j = 0; j < 8; ++j) acc[j] += (float)v[j];
      }
      f16x8 own = *(const f16x8*)&hs[(size_t)n * D + c0];
      float2 d2 = dnr[n];
      dr[k] = d2;
      ownr[k] = own;
      #pragma unroll
      for (int j = 0; j < 8; ++j) g[j] = (_Float16)(d2.x * (acc[j] + (float)own[j]));
    }
    *(f16x8*)&sA[lr * SA_STRIDE + c0] = g;
  }

  // ---- B fragments: wave w owns 16-col block w (loaded after gather, r10 order) ----
  f16x8 bf[4];
  #pragma unroll
  for (int kb = 0; kb < 4; ++kb)
    bf[kb] = Wf[(kb * 8 + wave) * 64 + lane];
  __syncthreads();

  // ---- MFMA: 64x128 A (4 row-tiles) x per-wave 16 cols ----
  f32x4 ca[4];
  #pragma unroll
  for (int rt = 0; rt < 4; ++rt) ca[rt] = (f32x4){0, 0, 0, 0};
  #pragma unroll
  for (int rt = 0; rt < 4; ++rt) {
    #pragma unroll
    for (int kb = 0; kb < 4; ++kb) {
      f16x8 a = *(const f16x8*)&sA[(rt * 16 + (lane & 15)) * SA_STRIDE + kb * 32 + (lane >> 4) * 8];
      ca[rt] = __builtin_amdgcn_mfma_f32_16x16x32_f16(a, bf[kb], ca[rt], 0, 0, 0);
    }
  }
  __syncthreads();   // all sA reads done before sC overwrites the same LDS

  // ---- stage C ----
  {
    int colb = wave * 16 + (lane & 15);
    int rowb = (lane >> 4) * 4;
    #pragma unroll
    for (int rt = 0; rt < 4; ++rt)
      #pragma unroll
      for (int r = 0; r < 4; ++r)
        sC[(rt * 16 + rowb + r) * SC_STRIDE + colb] = ca[rt][r];
  }
  __syncthreads();

  // ---- epilogue: 2 passes of 32 nodes; thread handles 8 features ----
  float4 b0 = *(const float4*)&bias[c0];
  float4 b1 = *(const float4*)&bias[c0 + 4];
  #pragma unroll
  for (int k = 0; k < 2; ++k) {
    int lr = ng + 32 * k;
    int n = node0 + lr;
    if (n >= N) continue;
    float v[8];
    float4 s0 = *(const float4*)&sC[lr * SC_STRIDE + c0];
    float4 s1 = *(const float4*)&sC[lr * SC_STRIDE + c0 + 4];
    v[0] = s0.x + b0.x; v[1] = s0.y + b0.y; v[2] = s0.z + b0.z; v[3] = s0.w + b0.w;
    v[4] = s1.x + b1.x; v[5] = s1.y + b1.y; v[6] = s1.z + b1.z; v[7] = s1.w + b1.w;
    size_t off = (size_t)n * D + c0;
    if (flags & 8) {     // h-add: h = hs_own * rdn (no global read)
      float rd = dr[k].y;
      #pragma unroll
      for (int j = 0; j < 8; ++j) v[j] += (float)ownr[k][j] * rd;
    }
    if (flags & 1) {
      f16x8 iv = *(const f16x8*)&init16in[off];
      #pragma unroll
      for (int j = 0; j < 8; ++j) v[j] += (float)iv[j];
    }
    if (flags & 2) {
      f16x8 o;
      #pragma unroll
      for (int j = 0; j < 8; ++j) o[j] = (_Float16)v[j];
      *(f16x8*)&init16out[off] = o;
    }
    if (flags & 4) {
      #pragma unroll
      for (int j = 0; j < 8; ++j) v[j] = fmaxf(v[j], 0.f);
    }
    if (flags & 32) {
      *(float4*)&out[off]     = make_float4(v[0], v[1], v[2], v[3]);
      *(float4*)&out[off + 4] = make_float4(v[4], v[5], v[6], v[7]);
    }
    if (flags & 16) {
      float dn = dr[k].x;
      f16x8 h8;
      #pragma unroll
      for (int j = 0; j < 8; ++j) h8[j] = (_Float16)(dn * v[j]);
      *(f16x8*)&hs_out[off] = h8;
    }
  }
}

// ---------------- launch ----------------

extern "C" void kernel_launch(void* const* d_in, const int* in_sizes, int n_in,
                              void* d_out, int out_size, void* d_ws, size_t ws_size,
                              hipStream_t stream) {
  const float* x = (const float*)d_in[0];
  const int* ei = (const int*)d_in[1];
  const float* Ws = (const float*)d_in[2];
  const float* bs = (const float*)d_in[3];
  float* out = (float*)d_out;

  const int N = in_sizes[0] / D;
  const int E = in_sizes[1] / 2;
  const int L = in_sizes[2] / (D * D);
  const int* src = ei;
  const int* dst = ei + E;

  uintptr_t p = (uintptr_t)d_ws;
  auto alloc = [&](size_t bytes) {
    uintptr_t r = p;
    p = (r + bytes + 255) & ~(uintptr_t)255;
    return r;
  };
  float2*    dnr      = (float2*)alloc((size_t)N * 8);
  int*       counts   = (int*)  alloc((size_t)N * 4);
  int*       row_ptr  = (int*)  alloc((size_t)(N + 1) * 4);
  int*       fillp    = (int*)  alloc((size_t)N * 4);
  int*       blksum   = (int*)  alloc((size_t)1024 * 4);
  int*       csr_src  = (int*)  alloc((size_t)E * 4);
  _Float16*  hs_a     = (_Float16*)alloc((size_t)N * D * 2);  // ping
  _Float16*  hs_b     = (_Float16*)alloc((size_t)N * D * 2);  // pong
  _Float16*  init16   = (_Float16*)alloc((size_t)N * D * 2);
  _Float16*  Wf       = (_Float16*)alloc((size_t)L * 4 * 8 * 64 * 8 * 2);

  const int NB = (N + SCAN_CH - 1) / SCAN_CH;

  hipMemsetAsync(counts, 0, (size_t)N * 4, stream);
  hist_kernel<<<8 * 192, 256, 0, stream>>>(dst, counts, E, N);
  dis_kernel<<<(N + 255) / 256, 256, 0, stream>>>(counts, dnr, N);
  scan_phaseA<<<NB, 256, 0, stream>>>(counts, blksum, N);
  scan_phaseB<<<1, 1024, 0, stream>>>(blksum, NB);
  scan_phaseC<<<NB, 256, 0, stream>>>(counts, blksum, row_ptr, fillp, N);
  fill_kernel<<<8 * 192, 256, 0, stream>>>(src, dst, fillp, csr_src, E, N);
  conv_x_kernel<<<(N * 16 + 255) / 256, 256, 0, stream>>>(x, dnr, hs_a, init16, N * 16);
  {
    int total = L * 2048;
    repack_w_kernel<<<(total + 255) / 256, 256, 0, stream>>>(Ws, Wf, total);
  }

  const int conv_grid = (N + NPB - 1) / NPB;
  _Float16* hsp[2] = {hs_a, hs_b};
  int cur = 0;

  for (int i = 0; i < L; ++i) {
    int flags;
    if (i == 0)          flags = 4 | 16;
    else if (i == L - 1) flags = 1 | 4 | 32;
    else                 flags = 1 | 2 | 4 | 16;
    conv_fused_kernel<<<conv_grid, CONV_THREADS, 0, stream>>>(hsp[cur], row_ptr, csr_src,
        dnr, (const f16x8*)(Wf + (size_t)i * 2048 * 8), bs + (size_t)i * D,
        init16, init16, out, hsp[cur ^ 1], N, flags);
    if (flags & 16) cur ^= 1;
    if (i < L - 1) {
      int j = (i == 0) ? (L - 1) : (i - 1);
      conv_fused_kernel<<<conv_grid, CONV_THREADS, 0, stream>>>(hsp[cur], row_ptr, csr_src,
          dnr, (const f16x8*)(Wf + (size_t)j * 2048 * 8), bs + (size_t)j * D,
          init16, init16, out, hsp[cur ^ 1], N, 8 | 16);
      cur ^= 1;
    }
  }
}